// Round 1
// baseline (403.440 us; speedup 1.0000x reference)
//
#include <hip/hip_runtime.h>
#include <math.h>

#define F_NODES 16384
#define DEG 8
#define E_TOT (F_NODES * DEG)   // 131072
#define B 64
#define H 16
#define LAYERS 10

// ---------------------------------------------------------------------------
// Transpose x0 (B, E) -> x0T (E, B). Tiled through LDS, both sides coalesced.
// Tile: 64 e-columns x 64 b-rows. Block = 256 threads, 16 elems/thread.
// LDS tile padded to 65 to keep bank aliasing at the free 2-way level.
// ---------------------------------------------------------------------------
__global__ __launch_bounds__(256) void transpose_in_kernel(
    const float* __restrict__ x0, float* __restrict__ xT)
{
    __shared__ float tile[64 * 65];
    const int e0 = blockIdx.x * 64;
    const int c  = threadIdx.x & 63;   // e offset within tile
    const int r  = threadIdx.x >> 6;   // 0..3

    #pragma unroll
    for (int i = 0; i < 16; ++i) {
        const int b = r + i * 4;
        tile[c * 65 + b] = x0[(size_t)b * E_TOT + e0 + c];
    }
    __syncthreads();
    const int b = threadIdx.x & 63;
    #pragma unroll
    for (int i = 0; i < 16; ++i) {
        const int el = r + i * 4;
        xT[(size_t)(e0 + el) * B + b] = tile[el * 65 + b];
    }
}

// ---------------------------------------------------------------------------
// One GSNN layer in transposed (E, B) layout. One wave per node f.
// lane = batch index b. Weights/biases/indices are wave-uniform -> scalar
// loads (readfirstlane on f), FMAs take the SGPR operand directly.
//   g[d]  = xin[ix[d]*B + lane]                 (coalesced 256B gathers)
//   h[j]  = elu( b1[f][j] + sum_d W1[f][j][d] * g[d] )
//   o[d]  = b2[f][d] + sum_j W2[f][d][j] * h[j]
//   out   = o + x0T (residual always to x0)
// FINAL=true writes d_out in the original (B, E) layout via 2x float4/lane.
// ---------------------------------------------------------------------------
template <bool FINAL>
__global__ __launch_bounds__(256) void layer_kernel(
    const float* __restrict__ xin,    // (E, B)
    const float* __restrict__ x0T,    // (E, B)
    const float* __restrict__ W1,     // (F, H, DEG)
    const float* __restrict__ b1,     // (F, H)
    const float* __restrict__ W2,     // (F, DEG, H)
    const float* __restrict__ b2,     // (F, DEG)
    const int*   __restrict__ in_ixs, // (F, DEG)
    float* __restrict__ xout)         // (E, B)  or (B, E) if FINAL
{
    const int lane = threadIdx.x & 63;
    const int wv   = threadIdx.x >> 6;          // 0..3
    const int f    = __builtin_amdgcn_readfirstlane((int)blockIdx.x * 4 + wv);

    // gather: indices are wave-uniform -> s_load; data loads coalesced
    const int* ixp = in_ixs + f * DEG;
    float g[DEG];
    #pragma unroll
    for (int d = 0; d < DEG; ++d) {
        const int ix = ixp[d];
        g[d] = xin[(size_t)ix * B + lane];
    }

    // h = elu(g @ W1^T + b1)
    const float* w1  = W1 + f * (H * DEG);
    const float* bb1 = b1 + f * H;
    float h[H];
    #pragma unroll
    for (int j = 0; j < H; ++j) {
        float acc = bb1[j];
        #pragma unroll
        for (int d = 0; d < DEG; ++d)
            acc = fmaf(w1[j * DEG + d], g[d], acc);
        h[j] = acc > 0.0f ? acc : expm1f(acc);
    }

    // o = h @ W2^T + b2 + residual(x0)
    const float* w2  = W2 + f * (DEG * H);
    const float* bb2 = b2 + f * DEG;
    float o[DEG];
    #pragma unroll
    for (int d = 0; d < DEG; ++d) {
        float acc = bb2[d];
        #pragma unroll
        for (int j = 0; j < H; ++j)
            acc = fmaf(w2[d * H + j], h[j], acc);
        o[d] = acc + x0T[(size_t)(f * DEG + d) * B + lane];
    }

    if (FINAL) {
        // write back in (B, E): lane b owns 8 consecutive floats at row b
        float4 v0 = make_float4(o[0], o[1], o[2], o[3]);
        float4 v1 = make_float4(o[4], o[5], o[6], o[7]);
        float4* dst = (float4*)(xout + (size_t)lane * E_TOT + f * DEG);
        dst[0] = v0;
        dst[1] = v1;
    } else {
        #pragma unroll
        for (int d = 0; d < DEG; ++d)
            xout[(size_t)(f * DEG + d) * B + lane] = o[d];
    }
}

extern "C" void kernel_launch(void* const* d_in, const int* in_sizes, int n_in,
                              void* d_out, int out_size, void* d_ws, size_t ws_size,
                              hipStream_t stream)
{
    const float* x0     = (const float*)d_in[0];
    const float* W1     = (const float*)d_in[1];
    const float* b1     = (const float*)d_in[2];
    const float* W2     = (const float*)d_in[3];
    const float* b2     = (const float*)d_in[4];
    const int*   in_ixs = (const int*)d_in[5];
    float* out = (float*)d_out;

    const size_t NEL = (size_t)E_TOT * B;   // 8.39M floats = 32 MB
    float* buf0 = (float*)d_ws;             // x0T, kept for residuals
    float* buf1 = buf0 + NEL;
    float* buf2 = buf1 + NEL;

    // x0 -> x0T (E, B)
    transpose_in_kernel<<<E_TOT / 64, 256, 0, stream>>>(x0, buf0);

    const float* cur = buf0;
    float* nxt = buf1;
    for (int l = 0; l < LAYERS; ++l) {
        if (l == LAYERS - 1) {
            layer_kernel<true><<<F_NODES / 4, 256, 0, stream>>>(
                cur, buf0, W1, b1, W2, b2, in_ixs, out);
        } else {
            layer_kernel<false><<<F_NODES / 4, 256, 0, stream>>>(
                cur, buf0, W1, b1, W2, b2, in_ixs, nxt);
            cur = nxt;
            nxt = (cur == buf1) ? buf2 : buf1;
        }
    }
}

// Round 2
// 359.413 us; speedup vs baseline: 1.1225x; 1.1225x over previous
//
#include <hip/hip_runtime.h>
#include <math.h>

#define F_NODES 16384
#define DEG 8
#define E_TOT (F_NODES * DEG)   // 131072
#define B 64
#define H 16
#define LAYERS 10

// ---------------------------------------------------------------------------
// Transpose x0 (B, E) -> x0T (E, B). Tiled through LDS, both sides coalesced.
// ---------------------------------------------------------------------------
__global__ __launch_bounds__(256) void transpose_in_kernel(
    const float* __restrict__ x0, float* __restrict__ xT)
{
    __shared__ float tile[64 * 65];
    const int e0 = blockIdx.x * 64;
    const int c  = threadIdx.x & 63;   // e offset within tile
    const int r  = threadIdx.x >> 6;   // 0..3

    #pragma unroll
    for (int i = 0; i < 16; ++i) {
        const int b = r + i * 4;
        tile[c * 65 + b] = x0[(size_t)b * E_TOT + e0 + c];
    }
    __syncthreads();
    const int b = threadIdx.x & 63;
    #pragma unroll
    for (int i = 0; i < 16; ++i) {
        const int el = r + i * 4;
        xT[(size_t)(e0 + el) * B + b] = tile[el * 65 + b];
    }
}

__device__ __forceinline__ float fast_elu(float x)
{
    // elu(x) = x>0 ? x : exp(x)-1 ; v_exp_f32 path, absolute err ~1e-7
    float e = __builtin_amdgcn_exp2f(x * 1.44269504088896340736f) - 1.0f;
    return x > 0.0f ? x : e;
}

// ---------------------------------------------------------------------------
// One GSNN layer in transposed (E, B) layout. One wave handles NPW nodes
// (unrolled for ILP: all gathers + residual loads + weight s_loads of both
// nodes can be in flight together). lane = batch index b. Weights/biases/
// indices are wave-uniform -> s_load; FMAs take the SGPR operand directly.
// ---------------------------------------------------------------------------
#define NPW 2   // nodes per wave

template <bool FINAL>
__global__ __launch_bounds__(256) void layer_kernel(
    const float* __restrict__ xin,    // (E, B)
    const float* __restrict__ x0T,    // (E, B)
    const float* __restrict__ W1,     // (F, H, DEG)
    const float* __restrict__ b1,     // (F, H)
    const float* __restrict__ W2,     // (F, DEG, H)
    const float* __restrict__ b2,     // (F, DEG)
    const int*   __restrict__ in_ixs, // (F, DEG)
    float* __restrict__ xout)         // (E, B)  or (B, E) if FINAL
{
    const int lane    = threadIdx.x & 63;
    const int wv      = threadIdx.x >> 6;                // 0..3
    const int wave_id = (int)blockIdx.x * 4 + wv;        // 0..F/NPW-1

    #pragma unroll
    for (int n = 0; n < NPW; ++n) {
        const int f = __builtin_amdgcn_readfirstlane(wave_id * NPW + n);

        // issue all global loads first: 8 gathers + 8 residual reads
        const int* ixp = in_ixs + f * DEG;
        float g[DEG], r[DEG];
        const float* resp = x0T + (size_t)f * DEG * B + lane;
        #pragma unroll
        for (int d = 0; d < DEG; ++d) {
            const int ix = ixp[d];
            g[d] = xin[(size_t)ix * B + lane];
            r[d] = resp[d * B];
        }

        // h = elu(g @ W1^T + b1)
        const float* w1  = W1 + f * (H * DEG);
        const float* bb1 = b1 + f * H;
        float h[H];
        #pragma unroll
        for (int j = 0; j < H; ++j) {
            float acc = bb1[j];
            #pragma unroll
            for (int d = 0; d < DEG; ++d)
                acc = fmaf(w1[j * DEG + d], g[d], acc);
            h[j] = fast_elu(acc);
        }

        // o = h @ W2^T + b2 + residual(x0)
        const float* w2  = W2 + f * (DEG * H);
        const float* bb2 = b2 + f * DEG;
        float o[DEG];
        #pragma unroll
        for (int d = 0; d < DEG; ++d) {
            float acc = bb2[d];
            #pragma unroll
            for (int j = 0; j < H; ++j)
                acc = fmaf(w2[d * H + j], h[j], acc);
            o[d] = acc + r[d];
        }

        if (FINAL) {
            // write back in (B, E): lane b owns 8 consecutive floats at row b
            float4 v0 = make_float4(o[0], o[1], o[2], o[3]);
            float4 v1 = make_float4(o[4], o[5], o[6], o[7]);
            float4* dst = (float4*)(xout + (size_t)lane * E_TOT + f * DEG);
            dst[0] = v0;
            dst[1] = v1;
        } else {
            float* outp = xout + (size_t)f * DEG * B + lane;
            #pragma unroll
            for (int d = 0; d < DEG; ++d)
                outp[d * B] = o[d];
        }
    }
}

extern "C" void kernel_launch(void* const* d_in, const int* in_sizes, int n_in,
                              void* d_out, int out_size, void* d_ws, size_t ws_size,
                              hipStream_t stream)
{
    const float* x0     = (const float*)d_in[0];
    const float* W1     = (const float*)d_in[1];
    const float* b1     = (const float*)d_in[2];
    const float* W2     = (const float*)d_in[3];
    const float* b2     = (const float*)d_in[4];
    const int*   in_ixs = (const int*)d_in[5];
    float* out = (float*)d_out;

    const size_t NEL = (size_t)E_TOT * B;   // 8.39M floats = 32 MB
    float* buf0 = (float*)d_ws;             // x0T, kept for residuals
    float* buf1 = buf0 + NEL;
    float* buf2 = buf1 + NEL;

    // x0 -> x0T (E, B)
    transpose_in_kernel<<<E_TOT / 64, 256, 0, stream>>>(x0, buf0);

    const int grid = F_NODES / (4 * NPW);
    const float* cur = buf0;
    float* nxt = buf1;
    for (int l = 0; l < LAYERS; ++l) {
        if (l == LAYERS - 1) {
            layer_kernel<true><<<grid, 256, 0, stream>>>(
                cur, buf0, W1, b1, W2, b2, in_ixs, out);
        } else {
            layer_kernel<false><<<grid, 256, 0, stream>>>(
                cur, buf0, W1, b1, W2, b2, in_ixs, nxt);
            cur = nxt;
            nxt = (cur == buf1) ? buf2 : buf1;
        }
    }
}